// Round 6
// baseline (310.400 us; speedup 1.0000x reference)
//
#include <hip/hip_runtime.h>
#include <hip/hip_bf16.h>
#include <cmath>
#include <cstdint>
#include <cstddef>

// Problem constants: B=4, C=256, H=W=256, DS=4 -> h=w=64, N=4096, Cq=16
typedef unsigned short u16;
typedef __attribute__((ext_vector_type(8))) __bf16 bf16x8;
typedef __attribute__((ext_vector_type(4))) float f32x4;
typedef __attribute__((ext_vector_type(8))) unsigned short us8;
typedef __attribute__((ext_vector_type(4))) unsigned short us4;

// Workspace layout (bytes)
static const size_t OFF_ODS   = 0;            // [B][C][4096] fp32: xd first, then out_ds (aliased)
static const size_t OFF_QT    = 16777216;     // [B][4096][16] fp32, 1 MB
static const size_t OFF_KT    = 17825792;     // [B][4096][16] fp32, 1 MB
static const size_t OFF_VT    = 18874368;     // [B][256][4096] bf16 (V transposed), 8 MB
static const size_t OFF_SPART = 27262976;     // [256 blocks][32] fp32 partial col-sums, 32 KB
static const size_t OFF_MEAN  = 27295744;     // 1 float

__device__ __forceinline__ void gl2lds16(const void* gsrc, void* ldst) {
  __builtin_amdgcn_global_load_lds(
      (const __attribute__((address_space(1))) unsigned int*)gsrc,
      (__attribute__((address_space(3))) unsigned int*)ldst, 16, 0, 0);
}

// ---------------- maxpool 4x4 (streaming, 16384 blocks) ----------------
__global__ __launch_bounds__(256) void k_pool(const float* __restrict__ x,
                                              float* __restrict__ xd) {
  unsigned idx = blockIdx.x * 256u + threadIdx.x;      // < 4*256*64*64
  unsigned xo = idx & 63u;
  unsigned yo = (idx >> 6) & 63u;
  unsigned bc = idx >> 12;                             // b*256 + c
  const float* base = x + (size_t)bc * 65536u + yo * 1024u + xo * 4u;
  float m = -1e30f;
#pragma unroll
  for (int dy = 0; dy < 4; ++dy) {
    float4 v = *reinterpret_cast<const float4*>(base + dy * 256);
    m = fmaxf(m, fmaxf(fmaxf(v.x, v.y), fmaxf(v.z, v.w)));
  }
  xd[(size_t)bc * 4096u + yo * 64u + xo] = m;
}

// ---------------- fused q/k/v 1x1 convs + per-block column sums ----------------
// 256 blocks (b x 64 token-strips of 64), 512 threads. Reads pooled xd (L2-hot).
__global__ __launch_bounds__(512) void k_qkv(const float* __restrict__ xd,
                                             const float* __restrict__ Wq, const float* __restrict__ bq,
                                             const float* __restrict__ Wk, const float* __restrict__ bk,
                                             const float* __restrict__ Wv, const float* __restrict__ bv,
                                             float* __restrict__ qT, float* __restrict__ kT,
                                             u16* __restrict__ vT, float* __restrict__ Spart) {
  __shared__ float smem[17408];   // union: xs[256][64] (16384) / part[8][64][33] (16896); red at +16896
  float (*xs)[64] = reinterpret_cast<float(*)[64]>(smem);
  float (*part)[64][33] = reinterpret_cast<float(*)[64][33]>(smem);
  float (*red)[32] = reinterpret_cast<float(*)[32]>(smem + 16896);
  const int b = blockIdx.x >> 6, n0 = (blockIdx.x & 63) * 64;
  const int tid = threadIdx.x;

  // ---- stage xd strip: 256 c x 64 tokens ----
  {
    const float* src = xd + (size_t)b * 1048576u + n0;
#pragma unroll
    for (int i = 0; i < 8; ++i) {
      int l4 = tid + i * 512;            // 0..4095 float4 slots
      int c = l4 >> 4, qq = l4 & 15;
      *reinterpret_cast<float4*>(&xs[c][qq * 4]) =
          *reinterpret_cast<const float4*>(src + (size_t)c * 4096u + qq * 4);
    }
  }
  __syncthreads();

  // ---- v conv: thread owns 8 out-channels x 4 tokens ----
  {
    const int ci = tid >> 4, ni = tid & 15;
    float vacc[8][4];
#pragma unroll
    for (int j = 0; j < 8; ++j) { vacc[j][0]=0.f; vacc[j][1]=0.f; vacc[j][2]=0.f; vacc[j][3]=0.f; }
    for (int cc4 = 0; cc4 < 64; ++cc4) {
      float4 xv0 = *reinterpret_cast<const float4*>(&xs[cc4*4+0][ni*4]);
      float4 xv1 = *reinterpret_cast<const float4*>(&xs[cc4*4+1][ni*4]);
      float4 xv2 = *reinterpret_cast<const float4*>(&xs[cc4*4+2][ni*4]);
      float4 xv3 = *reinterpret_cast<const float4*>(&xs[cc4*4+3][ni*4]);
#pragma unroll
      for (int j = 0; j < 8; ++j) {
        float4 wv = *reinterpret_cast<const float4*>(&Wv[(size_t)(ci*8 + j) * 256u + cc4*4]);
        vacc[j][0] = fmaf(wv.x, xv0.x, fmaf(wv.y, xv1.x, fmaf(wv.z, xv2.x, fmaf(wv.w, xv3.x, vacc[j][0]))));
        vacc[j][1] = fmaf(wv.x, xv0.y, fmaf(wv.y, xv1.y, fmaf(wv.z, xv2.y, fmaf(wv.w, xv3.y, vacc[j][1]))));
        vacc[j][2] = fmaf(wv.x, xv0.z, fmaf(wv.y, xv1.z, fmaf(wv.z, xv2.z, fmaf(wv.w, xv3.z, vacc[j][2]))));
        vacc[j][3] = fmaf(wv.x, xv0.w, fmaf(wv.y, xv1.w, fmaf(wv.z, xv2.w, fmaf(wv.w, xv3.w, vacc[j][3]))));
      }
    }
#pragma unroll
    for (int j = 0; j < 8; ++j) {
      int c = ci*8 + j;
      float bb = bv[c];
      us4 u;
#pragma unroll
      for (int nn = 0; nn < 4; ++nn)
        u[nn] = __builtin_bit_cast(u16, __float2bfloat16(vacc[j][nn] + bb));
      *reinterpret_cast<us4*>(vT + ((size_t)b*256 + c) * 4096u + n0 + ni*4) = u;
    }
  }

  // ---- q/k partials: thread owns token nl, c-range pp*32..+32 ----
  const int nl = tid & 63, pp = tid >> 6;
  float qa[16], ka[16];
#pragma unroll
  for (int o = 0; o < 16; ++o) { qa[o] = 0.f; ka[o] = 0.f; }
  for (int i = 0; i < 32; ++i) {
    int c = pp * 32 + i;
    float xv = xs[c][nl];
#pragma unroll
    for (int o = 0; o < 16; ++o) {
      qa[o] = fmaf(Wq[o * 256 + c], xv, qa[o]);
      ka[o] = fmaf(Wk[o * 256 + c], xv, ka[o]);
    }
  }
  __syncthreads();   // all xs reads done before part overwrite
#pragma unroll
  for (int o = 0; o < 16; ++o) {
    part[pp][nl][o]      = qa[o];
    part[pp][nl][16 + o] = ka[o];
  }
  __syncthreads();
  // final reduce -> qT/kT
#pragma unroll
  for (int i = 0; i < 4; ++i) {
    int idx = tid * 4 + i;
    int n = idx >> 5, o = idx & 31;
    float s = 0.f;
#pragma unroll
    for (int p = 0; p < 8; ++p) s += part[p][n][o];
    if (o < 16) qT[((size_t)b * 4096u + n0 + n) * 16u + o]        = s + bq[o];
    else        kT[((size_t)b * 4096u + n0 + n) * 16u + (o - 16)] = s + bk[o - 16];
  }
  // block column-sums (no bias; k_mean adds it) -> Spart[block][32]
  {
    int o = tid & 31, grp = tid >> 5;   // 16 grps x 4 tokens
    float s = 0.f;
#pragma unroll
    for (int nn = 0; nn < 4; ++nn) {
      int n = grp * 4 + nn;
#pragma unroll
      for (int p = 0; p < 8; ++p) s += part[p][n][o];
    }
    red[grp][o] = s;
  }
  __syncthreads();
  if (tid < 32) {
    float s = 0.f;
#pragma unroll
    for (int g = 0; g < 16; ++g) s += red[g][tid];
    Spart[(size_t)blockIdx.x * 32u + tid] = s;
  }
}

// ---------------- scalar mean of att from block partial sums ----------------
__global__ __launch_bounds__(64) void k_mean(const float* __restrict__ Spart,
                                             const float* __restrict__ bq, const float* __restrict__ bk,
                                             float* __restrict__ meanp) {
  int t = threadIdx.x;        // (b,o): b = t>>4, o = t&15
  int b = t >> 4, o = t & 15;
  float sq = 4096.0f * bq[o], sk = 4096.0f * bk[o];
  for (int blk = 0; blk < 64; ++blk) {
    const float* p = Spart + ((size_t)(b * 64 + blk)) * 32u;
    sq += p[o];
    sk += p[16 + o];
  }
  float pr = sq * sk;
#pragma unroll
  for (int off = 32; off > 0; off >>= 1) pr += __shfl_down(pr, off);
  if (t == 0) *meanp = pr * (1.0f / 67108864.0f);   // / (B*N*N)
}

// ---------------- one-pass MFMA flash: split-bf16 QK^T + masked softmax + PV ----------------
// 256 blocks, XCD-bijective remap: batch = bits1-2 of blockIdx -> each XCD serves ONE batch
// (2 MB V + 256 KB K fit its 4 MB L2). 512 threads = 8 waves (2/SIMD).
__global__ __launch_bounds__(512) void k_flash(const float* __restrict__ qT,
                                               const float* __restrict__ kT,
                                               const u16* __restrict__ vT,
                                               const float* __restrict__ meanp,
                                               float* __restrict__ ods) {
  __shared__ u16 vbuf[2][16384];       // [buf][c row(256) x kv(64)] linear, source-swizzled (64 KB)
  __shared__ u16 kfh[2][4][64][8];     // B-frag [k_hi|k_hi], fragment-linear (8 KB)
  __shared__ u16 kfl[2][4][64][8];     // B-frag [k_lo|k_lo] (8 KB)
  __shared__ u16 pfr[8][2][64][8];     // per-wave P A-frags (16 KB)

  const int orig = blockIdx.x;
  const int b    = (orig >> 1) & 3;                        // bits1-2 -> XCD pair per batch
  const int row0 = (((orig & 1) << 5) | (orig >> 3)) * 64; // bijective q-tile remap
  const int tid  = threadIdx.x;
  const int w    = tid >> 6;
  const int lane = tid & 63;
  const int wq   = w & 3;
  const int wc   = w >> 2;
  const int g    = lane >> 4;          // 0..3
  const int c16  = lane & 15;

  const float mean = *meanp;

  // ---- Q A-frags (split bf16: A1=[q_hi|q_lo], A2=[q_hi|0]) ----
  float qv[16];
  {
    const float* qrow = qT + ((size_t)b*4096 + row0 + 16*wq + c16) * 16;
#pragma unroll
    for (int i = 0; i < 4; ++i) {
      float4 t4 = reinterpret_cast<const float4*>(qrow)[i];
      qv[4*i] = t4.x; qv[4*i+1] = t4.y; qv[4*i+2] = t4.z; qv[4*i+3] = t4.w;
    }
  }
  u16 qhi[16], qlo[16];
#pragma unroll
  for (int i = 0; i < 16; ++i) {
    __hip_bfloat16 h = __float2bfloat16(qv[i]);
    float fh = __bfloat162float(h);
    __hip_bfloat16 lo = __float2bfloat16(qv[i] - fh);
    qhi[i] = __builtin_bit_cast(u16, h);
    qlo[i] = __builtin_bit_cast(u16, lo);
  }
  us8 a1u, a2u;
  {
    const bool koff8  = (g & 1);
    const bool lo_src = (g >= 2);
#pragma unroll
    for (int i = 0; i < 8; ++i) {
      u16 hs = koff8 ? qhi[i+8] : qhi[i];
      u16 ls = koff8 ? qlo[i+8] : qlo[i];
      a1u[i] = lo_src ? ls : hs;
      a2u[i] = lo_src ? (u16)0 : hs;
    }
  }
  const bf16x8 A1 = __builtin_bit_cast(bf16x8, a1u);
  const bf16x8 A2 = __builtin_bit_cast(bf16x8, a2u);

  f32x4 O[8];
#pragma unroll
  for (int i = 0; i < 8; ++i) O[i] = (f32x4){0.f, 0.f, 0.f, 0.f};
  float Lr[4] = {0.f, 0.f, 0.f, 0.f};
  float M = 0.0f;

  // K staging params (threads 0..255 only)
  const int kv_s = tid >> 2, t4v = tid & 3;
  const int ks = kv_s >> 4, kld0 = (kv_s & 15) + 16*(t4v >> 1), ki0 = 4*(t4v & 1);

  // ---- prologue: stage tile 0 ----
  {
    const u16* vsrc = vT + (size_t)b*256*4096;
#pragma unroll
    for (int i = 0; i < 4; ++i) {
      int u = i*512 + tid;
      int row = u >> 3, slot = u & 7;
      int sb = (slot*16) ^ ((row & 7) << 4);
      gl2lds16((const char*)(vsrc + (size_t)row*4096) + sb, (char*)&vbuf[0][0] + u*16);
    }
    if (tid < 256) {
      float4 kvec = *reinterpret_cast<const float4*>(kT + ((size_t)b*4096 + kv_s)*16 + 4*t4v);
      float kf[4] = {kvec.x, kvec.y, kvec.z, kvec.w};
      us4 h4, l4;
#pragma unroll
      for (int di = 0; di < 4; ++di) {
        __hip_bfloat16 h = __float2bfloat16(kf[di]);
        float fh = __bfloat162float(h);
        __hip_bfloat16 lo = __float2bfloat16(kf[di] - fh);
        h4[di] = __builtin_bit_cast(u16, h);
        l4[di] = __builtin_bit_cast(u16, lo);
      }
      *reinterpret_cast<us4*>(&kfh[0][ks][kld0][ki0])    = h4;
      *reinterpret_cast<us4*>(&kfh[0][ks][kld0+32][ki0]) = h4;
      *reinterpret_cast<us4*>(&kfl[0][ks][kld0][ki0])    = l4;
      *reinterpret_cast<us4*>(&kfl[0][ks][kld0+32][ki0]) = l4;
    }
  }
  __syncthreads();

  // ---- main loop over 64 KV tiles of 64 ----
  for (int t = 0; t < 64; ++t) {
    const int cur = t & 1, nxt = cur ^ 1;
    const int kv0n = ((t + 1) & 63) * 64;

    // [D] issue next-tile staging (K -> regs, V -> LDS via DMA)
    float4 kvec;
    if (tid < 256)
      kvec = *reinterpret_cast<const float4*>(kT + ((size_t)b*4096 + kv0n + kv_s)*16 + 4*t4v);
    {
      const u16* vsrc = vT + (size_t)b*256*4096 + kv0n;
#pragma unroll
      for (int i = 0; i < 4; ++i) {
        int u = i*512 + tid;
        int row = u >> 3, slot = u & 7;
        int sb = (slot*16) ^ ((row & 7) << 4);
        gl2lds16((const char*)(vsrc + (size_t)row*4096) + sb, (char*)&vbuf[nxt][0] + u*16);
      }
    }

    // [A] scores: 4 kv-subtiles x 2 MFMA (split-bf16)
    f32x4 S[4];
#pragma unroll
    for (int s = 0; s < 4; ++s) {
      bf16x8 bh = __builtin_bit_cast(bf16x8, *reinterpret_cast<const us8*>(&kfh[cur][s][lane][0]));
      bf16x8 bl = __builtin_bit_cast(bf16x8, *reinterpret_cast<const us8*>(&kfl[cur][s][lane][0]));
      f32x4 acc = (f32x4){0.f, 0.f, 0.f, 0.f};
      acc = __builtin_amdgcn_mfma_f32_16x16x32_bf16(A1, bh, acc, 0, 0, 0);
      acc = __builtin_amdgcn_mfma_f32_16x16x32_bf16(A2, bl, acc, 0, 0, 0);
      S[s] = acc;
    }

    // [B] mask + deferred-max online softmax (wave-wide M, THR=8)
    float pmax = -1e30f;
#pragma unroll
    for (int s = 0; s < 4; ++s)
#pragma unroll
      for (int r = 0; r < 4; ++r) {
        float v = S[s][r];
        v = (v < mean) ? 0.f : v;
        S[s][r] = v;
        pmax = fmaxf(pmax, v);
      }
    if (!__all(pmax <= M + 8.0f)) {
      float mw = pmax;
#pragma unroll
      for (int off = 1; off < 64; off <<= 1) mw = fmaxf(mw, __shfl_xor(mw, off));
      float Mn = fmaxf(M, mw);
      float sc = __expf(M - Mn);
#pragma unroll
      for (int i = 0; i < 8; ++i) {
        O[i][0] *= sc; O[i][1] *= sc; O[i][2] *= sc; O[i][3] *= sc;
      }
#pragma unroll
      for (int r = 0; r < 4; ++r) Lr[r] *= sc;
      M = Mn;
    }
    u16 pb[4][4];
#pragma unroll
    for (int s = 0; s < 4; ++s)
#pragma unroll
      for (int r = 0; r < 4; ++r) {
        float p = __expf(S[s][r] - M);
        Lr[r] += p;
        pb[s][r] = __builtin_bit_cast(u16, __float2bfloat16(p));
      }

    // [C] write P into per-wave A-frag copy
    {
      const int ib = lane & 7;
      const int t1 = (lane >> 3) & 1;
#pragma unroll
      for (int s = 0; s < 4; ++s) {
        const int c2 = s >> 1;
        const int ldb = 16 * ((2*s + t1) & 3) + 4*g;
#pragma unroll
        for (int r = 0; r < 4; ++r) pfr[w][c2][ldb + r][ib] = pb[s][r];
      }
    }
    asm volatile("s_waitcnt lgkmcnt(0)" ::: "memory");
    __builtin_amdgcn_sched_barrier(0);

    // [G] PV: 2 k-chunks x 8 c-subtiles (this wave's c-half)
#pragma unroll
    for (int c2 = 0; c2 < 2; ++c2) {
      bf16x8 pa = __builtin_bit_cast(bf16x8, *reinterpret_cast<const us8*>(&pfr[w][c2][lane][0]));
#pragma unroll
      for (int ct = 0; ct < 8; ++ct) {
        int row = (wc*8 + ct)*16 + c16;
        int off = (c2*64 + g*16) ^ ((lane & 7) << 4);
        bf16x8 vb = __builtin_bit_cast(bf16x8,
            *reinterpret_cast<const us8*>((const char*)&vbuf[cur][0] + row*128 + off));
        O[ct] = __builtin_amdgcn_mfma_f32_16x16x32_bf16(pa, vb, O[ct], 0, 0, 0);
      }
    }

    // [H] convert + write K frags for next tile
    if (tid < 256) {
      float kf[4] = {kvec.x, kvec.y, kvec.z, kvec.w};
      us4 h4, l4;
#pragma unroll
      for (int di = 0; di < 4; ++di) {
        __hip_bfloat16 h = __float2bfloat16(kf[di]);
        float fh = __bfloat162float(h);
        __hip_bfloat16 lo = __float2bfloat16(kf[di] - fh);
        h4[di] = __builtin_bit_cast(u16, h);
        l4[di] = __builtin_bit_cast(u16, lo);
      }
      *reinterpret_cast<us4*>(&kfh[nxt][ks][kld0][ki0])    = h4;
      *reinterpret_cast<us4*>(&kfh[nxt][ks][kld0+32][ki0]) = h4;
      *reinterpret_cast<us4*>(&kfl[nxt][ks][kld0][ki0])    = l4;
      *reinterpret_cast<us4*>(&kfl[nxt][ks][kld0+32][ki0]) = l4;
    }

    __syncthreads();
  }

  // ---- epilogue: reduce L across the 16 kv-lanes, write O/L to ods [b][c][n] ----
#pragma unroll
  for (int r = 0; r < 4; ++r) {
    float v = Lr[r];
#pragma unroll
    for (int off = 1; off < 16; off <<= 1) v += __shfl_xor(v, off);
    Lr[r] = v;
  }
  float inv[4];
#pragma unroll
  for (int r = 0; r < 4; ++r) inv[r] = 1.0f / Lr[r];
#pragma unroll
  for (int ct = 0; ct < 8; ++ct) {
    int c = (wc*8 + ct)*16 + c16;
    float* dst = ods + ((size_t)b*256 + c) * 4096u + row0 + 16*wq + 4*g;
    float4 o4 = make_float4(O[ct][0]*inv[0], O[ct][1]*inv[1], O[ct][2]*inv[2], O[ct][3]*inv[3]);
    *reinterpret_cast<float4*>(dst) = o4;
  }
}

// ---------------- bilinear 4x upsample + residual, 4 px/thread ----------------
__global__ __launch_bounds__(256) void k_up(const float* __restrict__ ods, const float* __restrict__ x,
                                            float* __restrict__ out) {
  unsigned idx4 = blockIdx.x * 256u + threadIdx.x;   // < 16777216
  int a  = (int)(idx4 & 63u);          // horizontal cell = output j strip [4a,4a+4)
  int i  = (int)((idx4 >> 6) & 255u);  // output row
  size_t bc = idx4 >> 14;              // b*256 + c

  float py = (i + 0.5f) * 0.25f - 0.5f;
  float y0f = floorf(py);
  float wy = py - y0f;
  int y0 = (int)y0f, y1 = y0 + 1;
  y0 = max(y0, 0); y1 = min(y1, 63);

  int xm1 = max(a - 1, 0), xp1 = min(a + 1, 63);

  const float* r0 = ods + bc * 4096u + y0 * 64;
  const float* r1 = ods + bc * 4096u + y1 * 64;
  float wy1 = 1.f - wy;
  float vm1 = wy1 * r0[xm1] + wy * r1[xm1];
  float v0  = wy1 * r0[a]   + wy * r1[a];
  float vp1 = wy1 * r0[xp1] + wy * r1[xp1];

  float4 xv = *reinterpret_cast<const float4*>(x + (size_t)idx4 * 4u);
  float4 o4;
  o4.x = fmaf(0.375f, vm1, 0.625f * v0) + xv.x;
  o4.y = fmaf(0.125f, vm1, 0.875f * v0) + xv.y;
  o4.z = fmaf(0.875f, v0, 0.125f * vp1) + xv.z;
  o4.w = fmaf(0.625f, v0, 0.375f * vp1) + xv.w;
  *reinterpret_cast<float4*>(out + (size_t)idx4 * 4u) = o4;
}

extern "C" void kernel_launch(void* const* d_in, const int* in_sizes, int n_in,
                              void* d_out, int out_size, void* d_ws, size_t ws_size,
                              hipStream_t stream) {
  const float* x  = (const float*)d_in[0];
  const float* Wq = (const float*)d_in[1];
  const float* bq = (const float*)d_in[2];
  const float* Wk = (const float*)d_in[3];
  const float* bk = (const float*)d_in[4];
  const float* Wv = (const float*)d_in[5];
  const float* bv = (const float*)d_in[6];
  float* out = (float*)d_out;

  char* ws = (char*)d_ws;
  float* xd    = (float*)(ws + OFF_ODS);   // xd first, ods later (aliased; xd dead after k_qkv)
  float* qT    = (float*)(ws + OFF_QT);
  float* kT    = (float*)(ws + OFF_KT);
  u16*   vT    = (u16*)(ws + OFF_VT);
  float* Spart = (float*)(ws + OFF_SPART);
  float* mnp   = (float*)(ws + OFF_MEAN);
  float* ods   = xd;

  k_pool<<<dim3(16384), dim3(256), 0, stream>>>(x, xd);
  k_qkv<<<dim3(256), dim3(512), 0, stream>>>(xd, Wq, bq, Wk, bk, Wv, bv, qT, kT, vT, Spart);
  k_mean<<<dim3(1), dim3(64), 0, stream>>>(Spart, bq, bk, mnp);
  k_flash<<<dim3(256), dim3(512), 0, stream>>>(qT, kT, vT, mnp, ods);
  k_up<<<dim3(65536), dim3(256), 0, stream>>>(ods, x, out);
}